// Round 1
// baseline (636.489 us; speedup 1.0000x reference)
//
#include <hip/hip_runtime.h>
#include <stdint.h>

// ---------------- types ----------------
typedef short bf16x8 __attribute__((ext_vector_type(8)));          // 8 bf16 in 4 VGPRs (MFMA A/B frag)
typedef float f32x4 __attribute__((ext_vector_type(4)));           // MFMA C/D frag
typedef unsigned short u16x8 __attribute__((ext_vector_type(8)));  // 16B bf16 store

#define N_NODES 50000
#define DIM 512
#define KDIM 1024
#define NPAD 50048              // 391 * 128
#define M_TILES 391
#define N_TILES 4
#define FLAT_TOTAL 25600000ULL  // N_NODES * DIM

__device__ __forceinline__ unsigned short f2bf(float f) {
    unsigned u = __float_as_uint(f);
    unsigned r = u + 0x7FFFu + ((u >> 16) & 1u);   // RNE
    return (unsigned short)(r >> 16);
}
__device__ __forceinline__ float bf2f(unsigned short h) {
    return __uint_as_float(((unsigned)h) << 16);
}

// async global -> LDS, 16B per lane. LDS dest must be wave-uniform base + lane*16.
__device__ __forceinline__ void llds16(const void* g, void* l) {
    __builtin_amdgcn_global_load_lds(
        (const __attribute__((address_space(1))) void*)g,
        (__attribute__((address_space(3))) void*)l,
        16, 0, 0);
}

// ---------------- W cast: fp32 [512,1024] -> bf16 bits ----------------
__global__ void cast_w(const float* __restrict__ w, unsigned short* __restrict__ o) {
    int i = (blockIdx.x * blockDim.x + threadIdx.x) * 8;   // 256*256*8 = 524288 exactly
    float4 v0 = *(const float4*)&w[i];
    float4 v1 = *(const float4*)&w[i + 4];
    u16x8 r;
    r[0] = f2bf(v0.x); r[1] = f2bf(v0.y); r[2] = f2bf(v0.z); r[3] = f2bf(v0.w);
    r[4] = f2bf(v1.x); r[5] = f2bf(v1.y); r[6] = f2bf(v1.z); r[7] = f2bf(v1.w);
    *(u16x8*)&o[i] = r;
}

// ---------------- A1 = [x | mean(x[n0],x[n1])] in bf16, one row per block ----------------
__global__ void build_a1(const float* __restrict__ x, const int* __restrict__ nb,
                         unsigned short* __restrict__ A) {
    int i = blockIdx.x;
    int t = threadIdx.x;
    u16x8 o;
    if (t < 64) {
        int c = t * 8;
        const float4* p = (const float4*)&x[(size_t)i * DIM + c];
        float4 a = p[0], b = p[1];
        o[0] = f2bf(a.x); o[1] = f2bf(a.y); o[2] = f2bf(a.z); o[3] = f2bf(a.w);
        o[4] = f2bf(b.x); o[5] = f2bf(b.y); o[6] = f2bf(b.z); o[7] = f2bf(b.w);
        *(u16x8*)&A[(size_t)i * KDIM + c] = o;
    } else {
        int c = (t - 64) * 8;
        int n0 = nb[i * 2], n1 = nb[i * 2 + 1];
        const float4* p0 = (const float4*)&x[(size_t)n0 * DIM + c];
        const float4* p1 = (const float4*)&x[(size_t)n1 * DIM + c];
        float4 a0 = p0[0], a1 = p0[1], b0 = p1[0], b1 = p1[1];
        o[0] = f2bf((a0.x + b0.x) * 0.5f); o[1] = f2bf((a0.y + b0.y) * 0.5f);
        o[2] = f2bf((a0.z + b0.z) * 0.5f); o[3] = f2bf((a0.w + b0.w) * 0.5f);
        o[4] = f2bf((a1.x + b1.x) * 0.5f); o[5] = f2bf((a1.y + b1.y) * 0.5f);
        o[6] = f2bf((a1.z + b1.z) * 0.5f); o[7] = f2bf((a1.w + b1.w) * 0.5f);
        *(u16x8*)&A[(size_t)i * KDIM + DIM + c] = o;
    }
}

// ---------------- A2 = [h1 | mean(h1[n0],h1[n1])] in bf16 ----------------
__global__ void build_a2(const unsigned short* __restrict__ h, const int* __restrict__ nb,
                         unsigned short* __restrict__ A) {
    int i = blockIdx.x;
    int t = threadIdx.x;
    if (t < 64) {
        int c = t * 8;
        *(u16x8*)&A[(size_t)i * KDIM + c] = *(const u16x8*)&h[(size_t)i * DIM + c];
    } else {
        int c = (t - 64) * 8;
        int n0 = nb[i * 2], n1 = nb[i * 2 + 1];
        u16x8 a = *(const u16x8*)&h[(size_t)n0 * DIM + c];
        u16x8 b = *(const u16x8*)&h[(size_t)n1 * DIM + c];
        u16x8 o;
#pragma unroll
        for (int j = 0; j < 8; j++) o[j] = f2bf((bf2f(a[j]) + bf2f(b[j])) * 0.5f);
        *(u16x8*)&A[(size_t)i * KDIM + DIM + c] = o;
    }
}

// ---------------- m97-style GEMM: C[M,512] = relu(A[M,1024] * B[512,1024]^T) ----------------
// OUT_MODE 0: store bf16 to h1 (no row guard, M=NPAD). OUT_MODE 1: store fp32, guard row < N_NODES.
template <int OUT_MODE>
__global__ __launch_bounds__(256)
void gemm_bt(const unsigned short* __restrict__ A, const unsigned short* __restrict__ B,
             void* __restrict__ C) {
    __shared__ unsigned short As[128 * 32];   // 8 KB, [row][k] rows of 64B
    __shared__ unsigned short Bs[128 * 32];   // 8 KB

    int t = threadIdx.x;
    int bm = blockIdx.x >> 2;         // N-tile fastest: 4 blocks share the A tile in L2
    int bn = blockIdx.x & 3;
    int lane = t & 63;
    int wave = t >> 6;
    int m_off = (wave >> 1) * 64;     // 2x2 waves over the 128x128 tile
    int n_off = (wave & 1) * 64;
    int lrow = lane & 15;
    int lk = (lane >> 4) * 8;

    f32x4 acc[4][4];
#pragma unroll
    for (int i = 0; i < 4; i++)
#pragma unroll
        for (int j = 0; j < 4; j++) acc[i][j] = (f32x4){0.f, 0.f, 0.f, 0.f};

    // staging addresses: thread t covers 16B chunk t and t+256 of the 8KB tile
    const unsigned short* ga = A + (size_t)(bm * 128 + (t >> 2)) * KDIM + (t & 3) * 8;
    const unsigned short* gb = B + (size_t)(bn * 128 + (t >> 2)) * KDIM + (t & 3) * 8;

    for (int k0 = 0; k0 < KDIM; k0 += 32) {
        __syncthreads();                       // prev iter's ds_reads done before overwrite
        llds16(ga + k0, &As[t * 8]);
        llds16(ga + k0 + 64 * KDIM, &As[t * 8 + 2048]);
        llds16(gb + k0, &Bs[t * 8]);
        llds16(gb + k0 + 64 * KDIM, &Bs[t * 8 + 2048]);
        __syncthreads();                       // drains vmcnt -> LDS valid

        bf16x8 af[4], bfr[4];
#pragma unroll
        for (int i = 0; i < 4; i++)
            af[i] = *(const bf16x8*)&As[(m_off + i * 16 + lrow) * 32 + lk];
#pragma unroll
        for (int j = 0; j < 4; j++)
            bfr[j] = *(const bf16x8*)&Bs[(n_off + j * 16 + lrow) * 32 + lk];
#pragma unroll
        for (int i = 0; i < 4; i++)
#pragma unroll
            for (int j = 0; j < 4; j++)
                acc[i][j] = __builtin_amdgcn_mfma_f32_16x16x32_bf16(af[i], bfr[j], acc[i][j], 0, 0, 0);
    }

    // epilogue: C/D layout col=lane&15, row=(lane>>4)*4+reg
    int lc = lane & 15;
    int lr = (lane >> 4) << 2;
#pragma unroll
    for (int i = 0; i < 4; i++) {
        int row0 = bm * 128 + m_off + i * 16 + lr;
#pragma unroll
        for (int j = 0; j < 4; j++) {
            int col = bn * 128 + n_off + j * 16 + lc;
            f32x4 v = acc[i][j];
            if (OUT_MODE == 0) {
                unsigned short* Cb = (unsigned short*)C;
#pragma unroll
                for (int r = 0; r < 4; r++)
                    Cb[(size_t)(row0 + r) * DIM + col] = f2bf(fmaxf(v[r], 0.f));
            } else {
                float* Cf = (float*)C;
#pragma unroll
                for (int r = 0; r < 4; r++)
                    if (row0 + r < N_NODES)
                        Cf[(size_t)(row0 + r) * DIM + col] = fmaxf(v[r], 0.f);
            }
        }
    }
}

// ---------------- FC: two 25.6M-long dot products ----------------
__global__ void zero2(float* p) { if (threadIdx.x < 2) p[threadIdx.x] = 0.f; }

__global__ void fc_reduce(const float* __restrict__ flat, const float* __restrict__ fcw,
                          float* __restrict__ partials) {
    float s0 = 0.f, s1 = 0.f;
    size_t stride = (size_t)gridDim.x * blockDim.x * 4;
    for (size_t i = ((size_t)blockIdx.x * blockDim.x + threadIdx.x) * 4; i < FLAT_TOTAL; i += stride) {
        float4 v  = *(const float4*)&flat[i];
        float4 w0 = *(const float4*)&fcw[i];
        float4 w1 = *(const float4*)&fcw[FLAT_TOTAL + i];
        s0 += v.x * w0.x + v.y * w0.y + v.z * w0.z + v.w * w0.w;
        s1 += v.x * w1.x + v.y * w1.y + v.z * w1.z + v.w * w1.w;
    }
#pragma unroll
    for (int off = 32; off > 0; off >>= 1) {
        s0 += __shfl_down(s0, off);
        s1 += __shfl_down(s1, off);
    }
    __shared__ float r0[4], r1[4];
    int lane = threadIdx.x & 63, w = threadIdx.x >> 6;
    if (lane == 0) { r0[w] = s0; r1[w] = s1; }
    __syncthreads();
    if (threadIdx.x == 0) {
        atomicAdd(&partials[0], r0[0] + r0[1] + r0[2] + r0[3]);
        atomicAdd(&partials[1], r1[0] + r1[1] + r1[2] + r1[3]);
    }
}

__global__ void finalize(const float* __restrict__ partials, const float* __restrict__ fcb,
                         float* __restrict__ out2) {
    float l0 = partials[0] + fcb[0];
    float l1 = partials[1] + fcb[1];
    float m = fmaxf(l0, l1);
    float lse = m + logf(expf(l0 - m) + expf(l1 - m));
    out2[0] = l0 - lse;
    out2[1] = l1 - lse;
}

// ---------------- launch ----------------
extern "C" void kernel_launch(void* const* d_in, const int* in_sizes, int n_in,
                              void* d_out, int out_size, void* d_ws, size_t ws_size,
                              hipStream_t stream) {
    const float* x   = (const float*)d_in[0];
    const int*   n1  = (const int*)d_in[1];
    const int*   n2  = (const int*)d_in[2];
    const float* W1  = (const float*)d_in[3];
    const float* W2  = (const float*)d_in[4];
    const float* fcw = (const float*)d_in[5];
    const float* fcb = (const float*)d_in[6];
    float* out = (float*)d_out;

    // workspace layout (all 16B aligned)
    char* ws = (char*)d_ws;
    const size_t A_OFF   = 0;                                  // NPAD*1024 bf16 = 102,498,304 B (reused for A1 then A2)
    const size_t H1_OFF  = A_OFF + (size_t)NPAD * KDIM * 2;    // NPAD*512 bf16 = 51,249,152 B
    const size_t W1_OFF  = H1_OFF + (size_t)NPAD * DIM * 2;
    const size_t W2_OFF  = W1_OFF + (size_t)DIM * KDIM * 2;
    const size_t P_OFF   = W2_OFF + (size_t)DIM * KDIM * 2;
    unsigned short* Abuf = (unsigned short*)(ws + A_OFF);
    unsigned short* H1   = (unsigned short*)(ws + H1_OFF);
    unsigned short* W1b  = (unsigned short*)(ws + W1_OFF);
    unsigned short* W2b  = (unsigned short*)(ws + W2_OFF);
    float* partials      = (float*)(ws + P_OFF);

    zero2<<<1, 64, 0, stream>>>(partials);
    cast_w<<<256, 256, 0, stream>>>(W1, W1b);
    cast_w<<<256, 256, 0, stream>>>(W2, W2b);

    build_a1<<<N_NODES, 128, 0, stream>>>(x, n1, Abuf);
    gemm_bt<0><<<M_TILES * N_TILES, 256, 0, stream>>>(Abuf, W1b, H1);
    build_a2<<<N_NODES, 128, 0, stream>>>(H1, n2, Abuf);
    gemm_bt<1><<<M_TILES * N_TILES, 256, 0, stream>>>(Abuf, W2b, out);

    fc_reduce<<<2048, 256, 0, stream>>>(out, fcw, partials);
    finalize<<<1, 1, 0, stream>>>(partials, fcb, out + FLAT_TOTAL);
}

// Round 2
// 585.552 us; speedup vs baseline: 1.0870x; 1.0870x over previous
//
#include <hip/hip_runtime.h>
#include <stdint.h>

// ---------------- types ----------------
typedef short bf16x8 __attribute__((ext_vector_type(8)));          // 8 bf16 in 4 VGPRs (MFMA A/B frag)
typedef float f32x4 __attribute__((ext_vector_type(4)));           // MFMA C/D frag
typedef unsigned short u16x8 __attribute__((ext_vector_type(8)));  // 16B bf16 chunk

#define N_NODES 50000
#define DIM 512                  // h width
#define TDIM 1024                // T = [P|Q] width
#define NPAD 50048               // 391 * 128
#define M_TILES 391
#define N_TILES 8                // TDIM / 128
#define FLAT_TOTAL 25600000ULL   // N_NODES * DIM
#define NBLK_COMB 12500          // N_NODES / 4 rows per block

__device__ __forceinline__ unsigned short f2bf(float f) {
    unsigned u = __float_as_uint(f);
    unsigned r = u + 0x7FFFu + ((u >> 16) & 1u);   // RNE
    return (unsigned short)(r >> 16);
}
__device__ __forceinline__ float bf2f(unsigned short h) {
    return __uint_as_float(((unsigned)h) << 16);
}

// async global -> LDS, 16B per lane. LDS dest must be wave-uniform base + lane*16.
__device__ __forceinline__ void llds16(const void* g, void* l) {
    __builtin_amdgcn_global_load_lds(
        (const __attribute__((address_space(1))) void*)g,
        (__attribute__((address_space(3))) void*)l,
        16, 0, 0);
}

// ---------------- cast x: fp32 [50000,512] -> bf16 ----------------
__global__ void cast_x(const float* __restrict__ x, unsigned short* __restrict__ o) {
    size_t i = ((size_t)blockIdx.x * blockDim.x + threadIdx.x) * 8;  // 12500*256*8 = 25.6M exactly
    float4 v0 = *(const float4*)&x[i];
    float4 v1 = *(const float4*)&x[i + 4];
    u16x8 r;
    r[0] = f2bf(v0.x); r[1] = f2bf(v0.y); r[2] = f2bf(v0.z); r[3] = f2bf(v0.w);
    r[4] = f2bf(v1.x); r[5] = f2bf(v1.y); r[6] = f2bf(v1.z); r[7] = f2bf(v1.w);
    *(u16x8*)&o[i] = r;
}

// ---------------- W [512,1024] -> Wsplit [1024,512] bf16 ----------------
// Wsplit[j,:] = W[j, :512] for j<512 (self part), = W[j-512, 512:] for j>=512 (neigh part)
__global__ void cast_w_split(const float* __restrict__ w, unsigned short* __restrict__ o) {
    int idx = (blockIdx.x * 256 + threadIdx.x) * 8;     // 256 blocks -> 524288 elems exactly
    int j = idx >> 9;
    int k = idx & 511;
    size_t src = (j < 512) ? ((size_t)j * 1024 + k) : ((size_t)(j - 512) * 1024 + 512 + k);
    float4 v0 = *(const float4*)&w[src];
    float4 v1 = *(const float4*)&w[src + 4];
    u16x8 r;
    r[0] = f2bf(v0.x); r[1] = f2bf(v0.y); r[2] = f2bf(v0.z); r[3] = f2bf(v0.w);
    r[4] = f2bf(v1.x); r[5] = f2bf(v1.y); r[6] = f2bf(v1.z); r[7] = f2bf(v1.w);
    *(u16x8*)&o[idx] = r;
}

// ---------------- GEMM: T[M,1024] = A[M,512] * B[1024,512]^T, bf16 out, no act ----------------
__global__ __launch_bounds__(256)
void gemm_nt(const unsigned short* __restrict__ A, const unsigned short* __restrict__ B,
             unsigned short* __restrict__ T) {
    __shared__ unsigned short As[128 * 32];   // 8 KB
    __shared__ unsigned short Bs[128 * 32];   // 8 KB

    int t = threadIdx.x;
    int bm = blockIdx.x >> 3;          // bn fastest: 8 blocks share the A tile in L2
    int bn = blockIdx.x & 7;
    int lane = t & 63;
    int wave = t >> 6;
    int m_off = (wave >> 1) * 64;      // 2x2 waves over the 128x128 tile
    int n_off = (wave & 1) * 64;
    int lrow = lane & 15;
    int lk = (lane >> 4) * 8;

    f32x4 acc[4][4];
#pragma unroll
    for (int i = 0; i < 4; i++)
#pragma unroll
        for (int j = 0; j < 4; j++) acc[i][j] = (f32x4){0.f, 0.f, 0.f, 0.f};

    // staging: thread t covers 16B chunk (row t>>2, chunk t&3) and same +64 rows
    const unsigned short* ga = A + (size_t)(bm * 128 + (t >> 2)) * DIM + (t & 3) * 8;
    const unsigned short* gb = B + (size_t)(bn * 128 + (t >> 2)) * DIM + (t & 3) * 8;

    for (int k0 = 0; k0 < DIM; k0 += 32) {     // 16 iterations
        __syncthreads();
        llds16(ga + k0, &As[t * 8]);
        llds16(ga + k0 + 64 * DIM, &As[t * 8 + 2048]);
        llds16(gb + k0, &Bs[t * 8]);
        llds16(gb + k0 + 64 * DIM, &Bs[t * 8 + 2048]);
        __syncthreads();

        bf16x8 af[4], bfr[4];
#pragma unroll
        for (int i = 0; i < 4; i++)
            af[i] = *(const bf16x8*)&As[(m_off + i * 16 + lrow) * 32 + lk];
#pragma unroll
        for (int j = 0; j < 4; j++)
            bfr[j] = *(const bf16x8*)&Bs[(n_off + j * 16 + lrow) * 32 + lk];
#pragma unroll
        for (int i = 0; i < 4; i++)
#pragma unroll
            for (int j = 0; j < 4; j++)
                acc[i][j] = __builtin_amdgcn_mfma_f32_16x16x32_bf16(af[i], bfr[j], acc[i][j], 0, 0, 0);
    }

    // epilogue: C/D layout col=lane&15, row=(lane>>4)*4+reg; raw bf16 (activation deferred)
    int lc = lane & 15;
    int lr = (lane >> 4) << 2;
#pragma unroll
    for (int i = 0; i < 4; i++) {
        int row0 = bm * 128 + m_off + i * 16 + lr;
#pragma unroll
        for (int j = 0; j < 4; j++) {
            int col = bn * 128 + n_off + j * 16 + lc;
            f32x4 v = acc[i][j];
#pragma unroll
            for (int r = 0; r < 4; r++)
                T[(size_t)(row0 + r) * TDIM + col] = f2bf(v[r]);
        }
    }
}

// ---------------- combine1: h1 = relu(P + 0.5*(Q[n0]+Q[n1])) -> bf16 ----------------
__global__ void combine1(const unsigned short* __restrict__ T, const int* __restrict__ nb,
                         unsigned short* __restrict__ H) {
    int t = threadIdx.x;
    int i = blockIdx.x * 4 + (t >> 6);          // 4 rows per block, one wave each
    int lane = t & 63;
    int c = lane * 8;
    int n0 = nb[i * 2], n1 = nb[i * 2 + 1];
    u16x8 p  = *(const u16x8*)&T[(size_t)i  * TDIM + c];
    u16x8 q0 = *(const u16x8*)&T[(size_t)n0 * TDIM + 512 + c];
    u16x8 q1 = *(const u16x8*)&T[(size_t)n1 * TDIM + 512 + c];
    u16x8 o;
#pragma unroll
    for (int j = 0; j < 8; j++)
        o[j] = f2bf(fmaxf(bf2f(p[j]) + 0.5f * (bf2f(q0[j]) + bf2f(q1[j])), 0.f));
    *(u16x8*)&H[(size_t)i * DIM + c] = o;
}

// ---------------- combine2: out = relu(P + 0.5*(Q[n0]+Q[n1])) fp32, + fused FC partials ----------------
__global__ void combine2(const unsigned short* __restrict__ T, const int* __restrict__ nb,
                         const float* __restrict__ fcw, float* __restrict__ out,
                         float2* __restrict__ partials) {
    int t = threadIdx.x;
    int i = blockIdx.x * 4 + (t >> 6);
    int lane = t & 63;
    int w = t >> 6;
    int c = lane * 8;
    int n0 = nb[i * 2], n1 = nb[i * 2 + 1];
    u16x8 p  = *(const u16x8*)&T[(size_t)i  * TDIM + c];
    u16x8 q0 = *(const u16x8*)&T[(size_t)n0 * TDIM + 512 + c];
    u16x8 q1 = *(const u16x8*)&T[(size_t)n1 * TDIM + 512 + c];
    float v[8];
#pragma unroll
    for (int j = 0; j < 8; j++)
        v[j] = fmaxf(bf2f(p[j]) + 0.5f * (bf2f(q0[j]) + bf2f(q1[j])), 0.f);
    size_t ob = (size_t)i * DIM + c;
    *(float4*)&out[ob]     = (float4){v[0], v[1], v[2], v[3]};
    *(float4*)&out[ob + 4] = (float4){v[4], v[5], v[6], v[7]};
    // fused FC dot partials
    float4 a0 = *(const float4*)&fcw[ob];
    float4 a1 = *(const float4*)&fcw[ob + 4];
    float4 b0 = *(const float4*)&fcw[FLAT_TOTAL + ob];
    float4 b1 = *(const float4*)&fcw[FLAT_TOTAL + ob + 4];
    float s0 = v[0]*a0.x + v[1]*a0.y + v[2]*a0.z + v[3]*a0.w
             + v[4]*a1.x + v[5]*a1.y + v[6]*a1.z + v[7]*a1.w;
    float s1 = v[0]*b0.x + v[1]*b0.y + v[2]*b0.z + v[3]*b0.w
             + v[4]*b1.x + v[5]*b1.y + v[6]*b1.z + v[7]*b1.w;
#pragma unroll
    for (int off = 32; off > 0; off >>= 1) {
        s0 += __shfl_down(s0, off);
        s1 += __shfl_down(s1, off);
    }
    __shared__ float r0[4], r1[4];
    if (lane == 0) { r0[w] = s0; r1[w] = s1; }
    __syncthreads();
    if (t == 0)
        partials[blockIdx.x] = make_float2(r0[0] + r0[1] + r0[2] + r0[3],
                                           r1[0] + r1[1] + r1[2] + r1[3]);
}

// ---------------- final reduce + log_softmax ----------------
__global__ void reduce_finalize(const float2* __restrict__ partials, const float* __restrict__ fcb,
                                float* __restrict__ out2) {
    float s0 = 0.f, s1 = 0.f;
    for (int k = threadIdx.x; k < NBLK_COMB; k += 1024) {
        float2 pr = partials[k];
        s0 += pr.x; s1 += pr.y;
    }
#pragma unroll
    for (int off = 32; off > 0; off >>= 1) {
        s0 += __shfl_down(s0, off);
        s1 += __shfl_down(s1, off);
    }
    __shared__ float r0[16], r1[16];
    int lane = threadIdx.x & 63, w = threadIdx.x >> 6;
    if (lane == 0) { r0[w] = s0; r1[w] = s1; }
    __syncthreads();
    if (threadIdx.x == 0) {
        float l0 = fcb[0], l1 = fcb[1];
#pragma unroll
        for (int k = 0; k < 16; k++) { l0 += r0[k]; l1 += r1[k]; }
        float m = fmaxf(l0, l1);
        float lse = m + logf(expf(l0 - m) + expf(l1 - m));
        out2[0] = l0 - lse;
        out2[1] = l1 - lse;
    }
}

// ---------------- launch ----------------
extern "C" void kernel_launch(void* const* d_in, const int* in_sizes, int n_in,
                              void* d_out, int out_size, void* d_ws, size_t ws_size,
                              hipStream_t stream) {
    const float* x   = (const float*)d_in[0];
    const int*   n1  = (const int*)d_in[1];
    const int*   n2  = (const int*)d_in[2];
    const float* W1  = (const float*)d_in[3];
    const float* W2  = (const float*)d_in[4];
    const float* fcw = (const float*)d_in[5];
    const float* fcb = (const float*)d_in[6];
    float* out = (float*)d_out;

    // workspace layout (16B aligned). Pad rows (50000..50047) stay 0xAA poison = tiny
    // finite bf16 values -> safe garbage through the GEMMs, never read by combine/out.
    char* ws = (char*)d_ws;
    const size_t XB_OFF  = 0;                                    // NPAD*512  bf16 = 51.2 MB
    const size_t T_OFF   = XB_OFF + (size_t)NPAD * DIM * 2;      // NPAD*1024 bf16 = 102.5 MB (reused both layers)
    const size_t H1_OFF  = T_OFF + (size_t)NPAD * TDIM * 2;      // NPAD*512  bf16 = 51.2 MB
    const size_t W1_OFF  = H1_OFF + (size_t)NPAD * DIM * 2;      // 1 MB
    const size_t W2_OFF  = W1_OFF + (size_t)TDIM * DIM * 2;      // 1 MB
    const size_t P_OFF   = W2_OFF + (size_t)TDIM * DIM * 2;      // 12500 float2
    unsigned short* Xb  = (unsigned short*)(ws + XB_OFF);
    unsigned short* T   = (unsigned short*)(ws + T_OFF);
    unsigned short* H1  = (unsigned short*)(ws + H1_OFF);
    unsigned short* W1s = (unsigned short*)(ws + W1_OFF);
    unsigned short* W2s = (unsigned short*)(ws + W2_OFF);
    float2* partials    = (float2*)(ws + P_OFF);

    cast_w_split<<<256, 256, 0, stream>>>(W1, W1s);
    cast_w_split<<<256, 256, 0, stream>>>(W2, W2s);
    cast_x<<<12500, 256, 0, stream>>>(x, Xb);

    gemm_nt<<<M_TILES * N_TILES, 256, 0, stream>>>(Xb, W1s, T);
    combine1<<<NBLK_COMB, 256, 0, stream>>>(T, n1, H1);
    gemm_nt<<<M_TILES * N_TILES, 256, 0, stream>>>(H1, W2s, T);
    combine2<<<NBLK_COMB, 256, 0, stream>>>(T, n2, fcw, out, partials);

    reduce_finalize<<<1, 1024, 0, stream>>>(partials, fcb, out + FLAT_TOTAL);
}

// Round 3
// 575.958 us; speedup vs baseline: 1.1051x; 1.0167x over previous
//
#include <hip/hip_runtime.h>
#include <stdint.h>

// ---------------- types ----------------
typedef short bf16x8 __attribute__((ext_vector_type(8)));          // 8 bf16 in 4 VGPRs (MFMA A/B frag)
typedef float f32x4 __attribute__((ext_vector_type(4)));           // MFMA C/D frag
typedef unsigned short u16x8 __attribute__((ext_vector_type(8)));  // 16B bf16 chunk

#define N_NODES 50000
#define DIM 512                  // h width (GEMM K)
#define TDIM 1024                // T = [P|Q] width (GEMM N)
#define NPAD 50048               // 391 * 128
#define M_TILES 391
#define N_TILES 8                // TDIM / 128
#define FLAT_TOTAL 25600000ULL   // N_NODES * DIM
#define NBLK_COMB 12500          // N_NODES / 4 rows per block

__device__ __forceinline__ unsigned short f2bf(float f) {
    unsigned u = __float_as_uint(f);
    unsigned r = u + 0x7FFFu + ((u >> 16) & 1u);   // RNE
    return (unsigned short)(r >> 16);
}
__device__ __forceinline__ float bf2f(unsigned short h) {
    return __uint_as_float(((unsigned)h) << 16);
}

// async global -> LDS, 16B per lane. LDS dest must be wave-uniform base + lane*16.
__device__ __forceinline__ void llds16(const void* g, void* l) {
    __builtin_amdgcn_global_load_lds(
        (const __attribute__((address_space(1))) void*)g,
        (__attribute__((address_space(3))) void*)l,
        16, 0, 0);
}

// ---------------- cast x: fp32 [50000,512] -> bf16 ----------------
__global__ void cast_x(const float* __restrict__ x, unsigned short* __restrict__ o) {
    size_t i = ((size_t)blockIdx.x * blockDim.x + threadIdx.x) * 8;  // 12500*256*8 = 25.6M exactly
    float4 v0 = *(const float4*)&x[i];
    float4 v1 = *(const float4*)&x[i + 4];
    u16x8 r;
    r[0] = f2bf(v0.x); r[1] = f2bf(v0.y); r[2] = f2bf(v0.z); r[3] = f2bf(v0.w);
    r[4] = f2bf(v1.x); r[5] = f2bf(v1.y); r[6] = f2bf(v1.z); r[7] = f2bf(v1.w);
    *(u16x8*)&o[i] = r;
}

// ---------------- both W [512,1024] -> Wsplit [1024,512] bf16, one launch ----------------
// Wsplit[j,:] = W[j, :512] for j<512 (self), = W[j-512, 512:] for j>=512 (neigh)
__global__ void cast_w_split2(const float* __restrict__ w1, const float* __restrict__ w2,
                              unsigned short* __restrict__ o1, unsigned short* __restrict__ o2) {
    int b = blockIdx.x;
    const float* w = (b < 256) ? w1 : w2;
    unsigned short* o = (b < 256) ? o1 : o2;
    int idx = ((b & 255) * 256 + threadIdx.x) * 8;     // 524288 elems per matrix
    int j = idx >> 9;
    int k = idx & 511;
    size_t src = (j < 512) ? ((size_t)j * 1024 + k) : ((size_t)(j - 512) * 1024 + 512 + k);
    float4 v0 = *(const float4*)&w[src];
    float4 v1 = *(const float4*)&w[src + 4];
    u16x8 r;
    r[0] = f2bf(v0.x); r[1] = f2bf(v0.y); r[2] = f2bf(v0.z); r[3] = f2bf(v0.w);
    r[4] = f2bf(v1.x); r[5] = f2bf(v1.y); r[6] = f2bf(v1.z); r[7] = f2bf(v1.w);
    *(u16x8*)&o[idx] = r;
}

// ---------------- GEMM: T[M,1024] = A[M,512] * B[1024,512]^T, bf16 out, no act ----------------
// BK=64: two 32-k sub-tiles staged per barrier pair -> 32 MFMA per vmcnt drain
// (was 16; the drain exposes ~300-900cyc of L2/HBM latency, so double the work under it).
__global__ __launch_bounds__(256)
void gemm_nt(const unsigned short* __restrict__ A, const unsigned short* __restrict__ B,
             unsigned short* __restrict__ T) {
    __shared__ unsigned short As[2][128 * 32];   // 2 x 8 KB (k-halves)
    __shared__ unsigned short Bs[2][128 * 32];   // 2 x 8 KB

    int t = threadIdx.x;
    int bm = blockIdx.x >> 3;          // bn fastest: with XCD round-robin (%8), each XCD
    int bn = blockIdx.x & 7;           //   keeps one B tile L2-hot; A tiles shared via L3
    int lane = t & 63;
    int wave = t >> 6;
    int m_off = (wave >> 1) * 64;      // 2x2 waves over the 128x128 tile
    int n_off = (wave & 1) * 64;
    int lrow = lane & 15;
    int lk = (lane >> 4) * 8;

    f32x4 acc[4][4];
#pragma unroll
    for (int i = 0; i < 4; i++)
#pragma unroll
        for (int j = 0; j < 4; j++) acc[i][j] = (f32x4){0.f, 0.f, 0.f, 0.f};

    // staging: thread t covers 16B chunk (row t>>2, chunk t&3) and same +64 rows
    const unsigned short* ga = A + (size_t)(bm * 128 + (t >> 2)) * DIM + (t & 3) * 8;
    const unsigned short* gb = B + (size_t)(bn * 128 + (t >> 2)) * DIM + (t & 3) * 8;

    for (int k0 = 0; k0 < DIM; k0 += 64) {     // 8 iterations
        __syncthreads();                       // prev iter's ds_reads done before overwrite
        llds16(ga + k0,            &As[0][t * 8]);
        llds16(ga + k0 + 64 * DIM, &As[0][t * 8 + 2048]);
        llds16(gb + k0,            &Bs[0][t * 8]);
        llds16(gb + k0 + 64 * DIM, &Bs[0][t * 8 + 2048]);
        llds16(ga + k0 + 32,            &As[1][t * 8]);
        llds16(ga + k0 + 32 + 64 * DIM, &As[1][t * 8 + 2048]);
        llds16(gb + k0 + 32,            &Bs[1][t * 8]);
        llds16(gb + k0 + 32 + 64 * DIM, &Bs[1][t * 8 + 2048]);
        __syncthreads();                       // drains vmcnt -> LDS valid

#pragma unroll
        for (int h = 0; h < 2; h++) {
            bf16x8 af[4], bfr[4];
#pragma unroll
            for (int i = 0; i < 4; i++)
                af[i] = *(const bf16x8*)&As[h][(m_off + i * 16 + lrow) * 32 + lk];
#pragma unroll
            for (int j = 0; j < 4; j++)
                bfr[j] = *(const bf16x8*)&Bs[h][(n_off + j * 16 + lrow) * 32 + lk];
#pragma unroll
            for (int i = 0; i < 4; i++)
#pragma unroll
                for (int j = 0; j < 4; j++)
                    acc[i][j] = __builtin_amdgcn_mfma_f32_16x16x32_bf16(af[i], bfr[j], acc[i][j], 0, 0, 0);
        }
    }

    // epilogue: C/D layout col=lane&15, row=(lane>>4)*4+reg; raw bf16 (activation deferred)
    int lc = lane & 15;
    int lr = (lane >> 4) << 2;
#pragma unroll
    for (int i = 0; i < 4; i++) {
        int row0 = bm * 128 + m_off + i * 16 + lr;
#pragma unroll
        for (int j = 0; j < 4; j++) {
            int col = bn * 128 + n_off + j * 16 + lc;
            f32x4 v = acc[i][j];
#pragma unroll
            for (int r = 0; r < 4; r++)
                T[(size_t)(row0 + r) * TDIM + col] = f2bf(v[r]);
        }
    }
}

// ---------------- combine1: h1 = relu(P + 0.5*(Q[n0]+Q[n1])) -> bf16 ----------------
__global__ void combine1(const unsigned short* __restrict__ T, const int* __restrict__ nb,
                         unsigned short* __restrict__ H) {
    int t = threadIdx.x;
    int i = blockIdx.x * 4 + (t >> 6);          // 4 rows per block, one wave each
    int lane = t & 63;
    int c = lane * 8;
    int n0 = nb[i * 2], n1 = nb[i * 2 + 1];
    u16x8 p  = *(const u16x8*)&T[(size_t)i  * TDIM + c];
    u16x8 q0 = *(const u16x8*)&T[(size_t)n0 * TDIM + 512 + c];
    u16x8 q1 = *(const u16x8*)&T[(size_t)n1 * TDIM + 512 + c];
    u16x8 o;
#pragma unroll
    for (int j = 0; j < 8; j++)
        o[j] = f2bf(fmaxf(bf2f(p[j]) + 0.5f * (bf2f(q0[j]) + bf2f(q1[j])), 0.f));
    *(u16x8*)&H[(size_t)i * DIM + c] = o;
}

// ---------------- combine2: out = relu(P + 0.5*(Q[n0]+Q[n1])) fp32, + fused FC partials ----------------
__global__ void combine2(const unsigned short* __restrict__ T, const int* __restrict__ nb,
                         const float* __restrict__ fcw, float* __restrict__ out,
                         float2* __restrict__ partials) {
    int t = threadIdx.x;
    int i = blockIdx.x * 4 + (t >> 6);
    int lane = t & 63;
    int w = t >> 6;
    int c = lane * 8;
    int n0 = nb[i * 2], n1 = nb[i * 2 + 1];
    u16x8 p  = *(const u16x8*)&T[(size_t)i  * TDIM + c];
    u16x8 q0 = *(const u16x8*)&T[(size_t)n0 * TDIM + 512 + c];
    u16x8 q1 = *(const u16x8*)&T[(size_t)n1 * TDIM + 512 + c];
    float v[8];
#pragma unroll
    for (int j = 0; j < 8; j++)
        v[j] = fmaxf(bf2f(p[j]) + 0.5f * (bf2f(q0[j]) + bf2f(q1[j])), 0.f);
    size_t ob = (size_t)i * DIM + c;
    *(float4*)&out[ob]     = (float4){v[0], v[1], v[2], v[3]};
    *(float4*)&out[ob + 4] = (float4){v[4], v[5], v[6], v[7]};
    // fused FC dot partials
    float4 a0 = *(const float4*)&fcw[ob];
    float4 a1 = *(const float4*)&fcw[ob + 4];
    float4 b0 = *(const float4*)&fcw[FLAT_TOTAL + ob];
    float4 b1 = *(const float4*)&fcw[FLAT_TOTAL + ob + 4];
    float s0 = v[0]*a0.x + v[1]*a0.y + v[2]*a0.z + v[3]*a0.w
             + v[4]*a1.x + v[5]*a1.y + v[6]*a1.z + v[7]*a1.w;
    float s1 = v[0]*b0.x + v[1]*b0.y + v[2]*b0.z + v[3]*b0.w
             + v[4]*b1.x + v[5]*b1.y + v[6]*b1.z + v[7]*b1.w;
#pragma unroll
    for (int off = 32; off > 0; off >>= 1) {
        s0 += __shfl_down(s0, off);
        s1 += __shfl_down(s1, off);
    }
    __shared__ float r0[4], r1[4];
    if (lane == 0) { r0[w] = s0; r1[w] = s1; }
    __syncthreads();
    if (t == 0)
        partials[blockIdx.x] = make_float2(r0[0] + r0[1] + r0[2] + r0[3],
                                           r1[0] + r1[1] + r1[2] + r1[3]);
}

// ---------------- final reduce + log_softmax ----------------
__global__ void reduce_finalize(const float2* __restrict__ partials, const float* __restrict__ fcb,
                                float* __restrict__ out2) {
    float s0 = 0.f, s1 = 0.f;
    for (int k = threadIdx.x; k < NBLK_COMB; k += 1024) {
        float2 pr = partials[k];
        s0 += pr.x; s1 += pr.y;
    }
#pragma unroll
    for (int off = 32; off > 0; off >>= 1) {
        s0 += __shfl_down(s0, off);
        s1 += __shfl_down(s1, off);
    }
    __shared__ float r0[16], r1[16];
    int lane = threadIdx.x & 63, w = threadIdx.x >> 6;
    if (lane == 0) { r0[w] = s0; r1[w] = s1; }
    __syncthreads();
    if (threadIdx.x == 0) {
        float l0 = fcb[0], l1 = fcb[1];
#pragma unroll
        for (int k = 0; k < 16; k++) { l0 += r0[k]; l1 += r1[k]; }
        float m = fmaxf(l0, l1);
        float lse = m + logf(expf(l0 - m) + expf(l1 - m));
        out2[0] = l0 - lse;
        out2[1] = l1 - lse;
    }
}

// ---------------- launch ----------------
extern "C" void kernel_launch(void* const* d_in, const int* in_sizes, int n_in,
                              void* d_out, int out_size, void* d_ws, size_t ws_size,
                              hipStream_t stream) {
    const float* x   = (const float*)d_in[0];
    const int*   n1  = (const int*)d_in[1];
    const int*   n2  = (const int*)d_in[2];
    const float* W1  = (const float*)d_in[3];
    const float* W2  = (const float*)d_in[4];
    const float* fcw = (const float*)d_in[5];
    const float* fcb = (const float*)d_in[6];
    float* out = (float*)d_out;

    // workspace layout (16B aligned). Pad rows (50000..50047) stay 0xAA poison = tiny
    // finite bf16 values -> safe garbage through the GEMMs, never read by combine/out.
    char* ws = (char*)d_ws;
    const size_t XB_OFF  = 0;                                    // NPAD*512  bf16 = 51.2 MB
    const size_t T_OFF   = XB_OFF + (size_t)NPAD * DIM * 2;      // NPAD*1024 bf16 = 102.5 MB (reused both layers)
    const size_t H1_OFF  = T_OFF + (size_t)NPAD * TDIM * 2;      // NPAD*512  bf16 = 51.2 MB
    const size_t W1_OFF  = H1_OFF + (size_t)NPAD * DIM * 2;      // 1 MB
    const size_t W2_OFF  = W1_OFF + (size_t)TDIM * DIM * 2;      // 1 MB
    const size_t P_OFF   = W2_OFF + (size_t)TDIM * DIM * 2;      // 12500 float2
    unsigned short* Xb  = (unsigned short*)(ws + XB_OFF);
    unsigned short* T   = (unsigned short*)(ws + T_OFF);
    unsigned short* H1  = (unsigned short*)(ws + H1_OFF);
    unsigned short* W1s = (unsigned short*)(ws + W1_OFF);
    unsigned short* W2s = (unsigned short*)(ws + W2_OFF);
    float2* partials    = (float2*)(ws + P_OFF);

    cast_w_split2<<<512, 256, 0, stream>>>(W1, W2, W1s, W2s);
    cast_x<<<12500, 256, 0, stream>>>(x, Xb);

    gemm_nt<<<M_TILES * N_TILES, 256, 0, stream>>>(Xb, W1s, T);
    combine1<<<NBLK_COMB, 256, 0, stream>>>(T, n1, H1);
    gemm_nt<<<M_TILES * N_TILES, 256, 0, stream>>>(H1, W2s, T);
    combine2<<<NBLK_COMB, 256, 0, stream>>>(T, n2, fcw, out, partials);

    reduce_finalize<<<1, 1024, 0, stream>>>(partials, fcb, out + FLAT_TOTAL);
}

// Round 4
// 551.605 us; speedup vs baseline: 1.1539x; 1.0441x over previous
//
#include <hip/hip_runtime.h>
#include <stdint.h>

// ---------------- types ----------------
typedef short bf16x8 __attribute__((ext_vector_type(8)));          // 8 bf16 in 4 VGPRs (MFMA A/B frag)
typedef float f32x4 __attribute__((ext_vector_type(4)));           // MFMA C/D frag
typedef unsigned short u16x8 __attribute__((ext_vector_type(8)));  // 16B bf16 chunk

#define N_NODES 50000
#define DIM 512                  // h width (GEMM K)
#define TDIM 1024                // T = [P|Q] width (GEMM N)
#define NPAD 50048               // 391 * 128
#define M_TILES 391
#define GEMM_GRID 3136           // 8 XCDs * 392 slots (8 idle guard blocks)
#define FLAT_TOTAL 25600000ULL   // N_NODES * DIM
#define NBLK_COMB 12500          // N_NODES / 4 rows per block

__device__ __forceinline__ unsigned short f2bf(float f) {
    unsigned u = __float_as_uint(f);
    unsigned r = u + 0x7FFFu + ((u >> 16) & 1u);   // RNE
    return (unsigned short)(r >> 16);
}
__device__ __forceinline__ float bf2f(unsigned short h) {
    return __uint_as_float(((unsigned)h) << 16);
}

// async global -> LDS, 16B per lane. LDS dest must be wave-uniform base + lane*16.
__device__ __forceinline__ void llds16(const void* g, void* l) {
    __builtin_amdgcn_global_load_lds(
        (const __attribute__((address_space(1))) void*)g,
        (__attribute__((address_space(3))) void*)l,
        16, 0, 0);
}

// ---------------- cast x: fp32 [50000,512] -> bf16 ----------------
__global__ void cast_x(const float* __restrict__ x, unsigned short* __restrict__ o) {
    size_t i = ((size_t)blockIdx.x * blockDim.x + threadIdx.x) * 8;  // 12500*256*8 = 25.6M exactly
    float4 v0 = *(const float4*)&x[i];
    float4 v1 = *(const float4*)&x[i + 4];
    u16x8 r;
    r[0] = f2bf(v0.x); r[1] = f2bf(v0.y); r[2] = f2bf(v0.z); r[3] = f2bf(v0.w);
    r[4] = f2bf(v1.x); r[5] = f2bf(v1.y); r[6] = f2bf(v1.z); r[7] = f2bf(v1.w);
    *(u16x8*)&o[i] = r;
}

// ---------------- both W [512,1024] -> Wsplit [1024,512] bf16, one launch ----------------
// Wsplit[j,:] = W[j, :512] for j<512 (self), = W[j-512, 512:] for j>=512 (neigh)
__global__ void cast_w_split2(const float* __restrict__ w1, const float* __restrict__ w2,
                              unsigned short* __restrict__ o1, unsigned short* __restrict__ o2) {
    int b = blockIdx.x;
    const float* w = (b < 256) ? w1 : w2;
    unsigned short* o = (b < 256) ? o1 : o2;
    int idx = ((b & 255) * 256 + threadIdx.x) * 8;     // 524288 elems per matrix
    int j = idx >> 9;
    int k = idx & 511;
    size_t src = (j < 512) ? ((size_t)j * 1024 + k) : ((size_t)(j - 512) * 1024 + 512 + k);
    float4 v0 = *(const float4*)&w[src];
    float4 v1 = *(const float4*)&w[src + 4];
    u16x8 r;
    r[0] = f2bf(v0.x); r[1] = f2bf(v0.y); r[2] = f2bf(v0.z); r[3] = f2bf(v0.w);
    r[4] = f2bf(v1.x); r[5] = f2bf(v1.y); r[6] = f2bf(v1.z); r[7] = f2bf(v1.w);
    *(u16x8*)&o[idx] = r;
}

// ---------------- GEMM: T[M,1024] = A[M,512] * B[1024,512]^T, bf16 out, no act ----------------
// XCD-affinity swizzle: assuming round-robin block->XCD (%8), XCD x owns all bm with
// bm%8==x, and the 8 bn-blocks of one bm are adjacent in dispatch order -> A-tile is
// fetched from HBM once and re-read 7x from that XCD's own L2 (prev layout staged each
// A-tile on 8 different, non-coherent XCD L2s = 8x A traffic from L3/HBM).
__global__ __launch_bounds__(256)
void gemm_nt(const unsigned short* __restrict__ A, const unsigned short* __restrict__ B,
             unsigned short* __restrict__ T) {
    __shared__ unsigned short As[2][128 * 32];   // 2 x 8 KB (k-halves)
    __shared__ unsigned short Bs[2][128 * 32];   // 2 x 8 KB

    int x = blockIdx.x & 7;            // XCD id (round-robin heuristic)
    int g = blockIdx.x >> 3;           // 0..391 within XCD
    int bm = x + 8 * (g >> 3);         // bm % 8 == x; concurrent bm-group working set ~3MB < 4MB L2
    int bn = g & 7;
    if (bm >= M_TILES) return;         // 8 guard blocks idle (x=7, last group)

    int t = threadIdx.x;
    int lane = t & 63;
    int wave = t >> 6;
    int m_off = (wave >> 1) * 64;      // 2x2 waves over the 128x128 tile
    int n_off = (wave & 1) * 64;
    int lrow = lane & 15;
    int lk = (lane >> 4) * 8;

    f32x4 acc[4][4];
#pragma unroll
    for (int i = 0; i < 4; i++)
#pragma unroll
        for (int j = 0; j < 4; j++) acc[i][j] = (f32x4){0.f, 0.f, 0.f, 0.f};

    // staging: thread t covers 16B chunk (row t>>2, chunk t&3) and same +64 rows
    const unsigned short* ga = A + (size_t)(bm * 128 + (t >> 2)) * DIM + (t & 3) * 8;
    const unsigned short* gb = B + (size_t)(bn * 128 + (t >> 2)) * DIM + (t & 3) * 8;

    for (int k0 = 0; k0 < DIM; k0 += 64) {     // 8 iterations
        __syncthreads();                       // prev iter's ds_reads done before overwrite
        llds16(ga + k0,            &As[0][t * 8]);
        llds16(ga + k0 + 64 * DIM, &As[0][t * 8 + 2048]);
        llds16(gb + k0,            &Bs[0][t * 8]);
        llds16(gb + k0 + 64 * DIM, &Bs[0][t * 8 + 2048]);
        llds16(ga + k0 + 32,            &As[1][t * 8]);
        llds16(ga + k0 + 32 + 64 * DIM, &As[1][t * 8 + 2048]);
        llds16(gb + k0 + 32,            &Bs[1][t * 8]);
        llds16(gb + k0 + 32 + 64 * DIM, &Bs[1][t * 8 + 2048]);
        __syncthreads();                       // drains vmcnt -> LDS valid

#pragma unroll
        for (int h = 0; h < 2; h++) {
            bf16x8 af[4], bfr[4];
#pragma unroll
            for (int i = 0; i < 4; i++)
                af[i] = *(const bf16x8*)&As[h][(m_off + i * 16 + lrow) * 32 + lk];
#pragma unroll
            for (int j = 0; j < 4; j++)
                bfr[j] = *(const bf16x8*)&Bs[h][(n_off + j * 16 + lrow) * 32 + lk];
#pragma unroll
            for (int i = 0; i < 4; i++)
#pragma unroll
                for (int j = 0; j < 4; j++)
                    acc[i][j] = __builtin_amdgcn_mfma_f32_16x16x32_bf16(af[i], bfr[j], acc[i][j], 0, 0, 0);
        }
    }

    // epilogue: C/D layout col=lane&15, row=(lane>>4)*4+reg; raw bf16 (activation deferred)
    int lc = lane & 15;
    int lr = (lane >> 4) << 2;
#pragma unroll
    for (int i = 0; i < 4; i++) {
        int row0 = bm * 128 + m_off + i * 16 + lr;
#pragma unroll
        for (int j = 0; j < 4; j++) {
            int col = bn * 128 + n_off + j * 16 + lc;
            f32x4 v = acc[i][j];
#pragma unroll
            for (int r = 0; r < 4; r++)
                T[(size_t)(row0 + r) * TDIM + col] = f2bf(v[r]);
        }
    }
}

// ---------------- combine1: h1 = relu(P + 0.5*(Q[n0]+Q[n1])) -> bf16 ----------------
__global__ void combine1(const unsigned short* __restrict__ T, const int* __restrict__ nb,
                         unsigned short* __restrict__ H) {
    int t = threadIdx.x;
    int i = blockIdx.x * 4 + (t >> 6);          // 4 rows per block, one wave each
    int lane = t & 63;
    int c = lane * 8;
    int n0 = nb[i * 2], n1 = nb[i * 2 + 1];
    u16x8 p  = *(const u16x8*)&T[(size_t)i  * TDIM + c];
    u16x8 q0 = *(const u16x8*)&T[(size_t)n0 * TDIM + 512 + c];
    u16x8 q1 = *(const u16x8*)&T[(size_t)n1 * TDIM + 512 + c];
    u16x8 o;
#pragma unroll
    for (int j = 0; j < 8; j++)
        o[j] = f2bf(fmaxf(bf2f(p[j]) + 0.5f * (bf2f(q0[j]) + bf2f(q1[j])), 0.f));
    *(u16x8*)&H[(size_t)i * DIM + c] = o;
}

// ---------------- combine2: out = relu(P + 0.5*(Q[n0]+Q[n1])) fp32, + fused FC partials ----------------
__global__ void combine2(const unsigned short* __restrict__ T, const int* __restrict__ nb,
                         const float* __restrict__ fcw, float* __restrict__ out,
                         float2* __restrict__ partials) {
    int t = threadIdx.x;
    int i = blockIdx.x * 4 + (t >> 6);
    int lane = t & 63;
    int w = t >> 6;
    int c = lane * 8;
    int n0 = nb[i * 2], n1 = nb[i * 2 + 1];
    u16x8 p  = *(const u16x8*)&T[(size_t)i  * TDIM + c];
    u16x8 q0 = *(const u16x8*)&T[(size_t)n0 * TDIM + 512 + c];
    u16x8 q1 = *(const u16x8*)&T[(size_t)n1 * TDIM + 512 + c];
    float v[8];
#pragma unroll
    for (int j = 0; j < 8; j++)
        v[j] = fmaxf(bf2f(p[j]) + 0.5f * (bf2f(q0[j]) + bf2f(q1[j])), 0.f);
    size_t ob = (size_t)i * DIM + c;
    *(float4*)&out[ob]     = (float4){v[0], v[1], v[2], v[3]};
    *(float4*)&out[ob + 4] = (float4){v[4], v[5], v[6], v[7]};
    // fused FC dot partials
    float4 a0 = *(const float4*)&fcw[ob];
    float4 a1 = *(const float4*)&fcw[ob + 4];
    float4 b0 = *(const float4*)&fcw[FLAT_TOTAL + ob];
    float4 b1 = *(const float4*)&fcw[FLAT_TOTAL + ob + 4];
    float s0 = v[0]*a0.x + v[1]*a0.y + v[2]*a0.z + v[3]*a0.w
             + v[4]*a1.x + v[5]*a1.y + v[6]*a1.z + v[7]*a1.w;
    float s1 = v[0]*b0.x + v[1]*b0.y + v[2]*b0.z + v[3]*b0.w
             + v[4]*b1.x + v[5]*b1.y + v[6]*b1.z + v[7]*b1.w;
#pragma unroll
    for (int off = 32; off > 0; off >>= 1) {
        s0 += __shfl_down(s0, off);
        s1 += __shfl_down(s1, off);
    }
    __shared__ float r0[4], r1[4];
    if (lane == 0) { r0[w] = s0; r1[w] = s1; }
    __syncthreads();
    if (t == 0)
        partials[blockIdx.x] = make_float2(r0[0] + r0[1] + r0[2] + r0[3],
                                           r1[0] + r1[1] + r1[2] + r1[3]);
}

// ---------------- final reduce + log_softmax ----------------
__global__ void reduce_finalize(const float2* __restrict__ partials, const float* __restrict__ fcb,
                                float* __restrict__ out2) {
    float s0 = 0.f, s1 = 0.f;
    for (int k = threadIdx.x; k < NBLK_COMB; k += 1024) {
        float2 pr = partials[k];
        s0 += pr.x; s1 += pr.y;
    }
#pragma unroll
    for (int off = 32; off > 0; off >>= 1) {
        s0 += __shfl_down(s0, off);
        s1 += __shfl_down(s1, off);
    }
    __shared__ float r0[16], r1[16];
    int lane = threadIdx.x & 63, w = threadIdx.x >> 6;
    if (lane == 0) { r0[w] = s0; r1[w] = s1; }
    __syncthreads();
    if (threadIdx.x == 0) {
        float l0 = fcb[0], l1 = fcb[1];
#pragma unroll
        for (int k = 0; k < 16; k++) { l0 += r0[k]; l1 += r1[k]; }
        float m = fmaxf(l0, l1);
        float lse = m + logf(expf(l0 - m) + expf(l1 - m));
        out2[0] = l0 - lse;
        out2[1] = l1 - lse;
    }
}

// ---------------- launch ----------------
extern "C" void kernel_launch(void* const* d_in, const int* in_sizes, int n_in,
                              void* d_out, int out_size, void* d_ws, size_t ws_size,
                              hipStream_t stream) {
    const float* x   = (const float*)d_in[0];
    const int*   n1  = (const int*)d_in[1];
    const int*   n2  = (const int*)d_in[2];
    const float* W1  = (const float*)d_in[3];
    const float* W2  = (const float*)d_in[4];
    const float* fcw = (const float*)d_in[5];
    const float* fcb = (const float*)d_in[6];
    float* out = (float*)d_out;

    // workspace layout (16B aligned). Pad rows (50000..50047) stay 0xAA poison = tiny
    // finite bf16 values -> safe garbage through the GEMMs, never read by combine/out.
    char* ws = (char*)d_ws;
    const size_t XB_OFF  = 0;                                    // NPAD*512  bf16 = 51.2 MB
    const size_t T_OFF   = XB_OFF + (size_t)NPAD * DIM * 2;      // NPAD*1024 bf16 = 102.5 MB (reused both layers)
    const size_t H1_OFF  = T_OFF + (size_t)NPAD * TDIM * 2;      // NPAD*512  bf16 = 51.2 MB
    const size_t W1_OFF  = H1_OFF + (size_t)NPAD * DIM * 2;      // 1 MB
    const size_t W2_OFF  = W1_OFF + (size_t)TDIM * DIM * 2;      // 1 MB
    const size_t P_OFF   = W2_OFF + (size_t)TDIM * DIM * 2;      // 12500 float2
    unsigned short* Xb  = (unsigned short*)(ws + XB_OFF);
    unsigned short* T   = (unsigned short*)(ws + T_OFF);
    unsigned short* H1  = (unsigned short*)(ws + H1_OFF);
    unsigned short* W1s = (unsigned short*)(ws + W1_OFF);
    unsigned short* W2s = (unsigned short*)(ws + W2_OFF);
    float2* partials    = (float2*)(ws + P_OFF);

    cast_w_split2<<<512, 256, 0, stream>>>(W1, W2, W1s, W2s);
    cast_x<<<12500, 256, 0, stream>>>(x, Xb);

    gemm_nt<<<GEMM_GRID, 256, 0, stream>>>(Xb, W1s, T);
    combine1<<<NBLK_COMB, 256, 0, stream>>>(T, n1, H1);
    gemm_nt<<<GEMM_GRID, 256, 0, stream>>>(H1, W2s, T);
    combine2<<<NBLK_COMB, 256, 0, stream>>>(T, n2, fcw, out, partials);

    reduce_finalize<<<1, 1024, 0, stream>>>(partials, fcb, out + FLAT_TOTAL);
}